// Round 16
// baseline (438.983 us; speedup 1.0000x reference)
//
#include <hip/hip_runtime.h>
#include <math.h>

#define N_NODES 20000
#define N_EDGES 256000

typedef __attribute__((ext_vector_type(8))) short bf16x8;
typedef __attribute__((ext_vector_type(4))) float f32x4;

__device__ inline unsigned short f2b(float f) {
    unsigned u = __builtin_bit_cast(unsigned, f);
    unsigned r = (u + 0x7fffu + ((u >> 16) & 1u)) >> 16;
    return (unsigned short)r;
}
__device__ inline float b2f(unsigned short s) {
    return __builtin_bit_cast(float, ((unsigned)s) << 16);
}

// ---------------- CSR build ----------------

__global__ void zero2_kernel(int* __restrict__ a, int* __restrict__ b, int n) {
    int i = blockIdx.x * blockDim.x + threadIdx.x;
    if (i < n) { a[i] = 0; b[i] = 0; }
}

__global__ void hist_kernel(const int* __restrict__ dst, int* __restrict__ deg) {
    int i = blockIdx.x * blockDim.x + threadIdx.x;
    if (i < N_EDGES) atomicAdd(&deg[dst[i]], 1);
}

#define SCAN_T 1024
#define SCAN_CH 20

__global__ __launch_bounds__(1024) void scan_kernel(const int* __restrict__ deg,
                                                    int* __restrict__ offsets) {
    __shared__ int sums[SCAN_T];
    int tid = threadIdx.x;
    int base = tid * SCAN_CH;
    int vals[SCAN_CH];
    int local = 0;
#pragma unroll
    for (int i = 0; i < SCAN_CH; ++i) {
        int idx = base + i;
        int v = (idx < N_NODES) ? deg[idx] : 0;
        vals[i] = v;
        local += v;
    }
    sums[tid] = local;
    __syncthreads();
    for (int off = 1; off < SCAN_T; off <<= 1) {
        int t = (tid >= off) ? sums[tid - off] : 0;
        __syncthreads();
        sums[tid] += t;
        __syncthreads();
    }
    int run = (tid > 0) ? sums[tid - 1] : 0;
    if (tid == 0) offsets[0] = 0;
#pragma unroll
    for (int i = 0; i < SCAN_CH; ++i) {
        int idx = base + i;
        if (idx < N_NODES) {
            run += vals[i];
            offsets[idx + 1] = run;
        }
    }
}

__global__ void scatter_kernel(const int* __restrict__ dst, const int* __restrict__ src,
                               const int* __restrict__ offsets,
                               int* __restrict__ cursor, int* __restrict__ csrc) {
    int i = blockIdx.x * blockDim.x + threadIdx.x;
    if (i < N_EDGES) {
        int d = dst[i];
        int p = offsets[d] + atomicAdd(&cursor[d], 1);
        csrc[p] = src[i];
    }
}

// ---------------- fused prep: x->bf16 + 3 weight transpose-casts ----------------

#define PR0 (N_NODES * 128 / 4)
#define PR1 (128 * 400)
#define PR2 (400 * 800)
#define PR3 (800 * 64)

__global__ void prep_kernel(const float* __restrict__ x, const float* __restrict__ W1,
                            const float* __restrict__ W2, const float* __restrict__ W3,
                            unsigned short* __restrict__ bufX, unsigned short* __restrict__ Wt1,
                            unsigned short* __restrict__ Wt2, unsigned short* __restrict__ Wt3) {
    int id = blockIdx.x * blockDim.x + threadIdx.x;
    if (id < PR0) {
        float4 v = ((const float4*)x)[id];
        ushort4 u;
        u.x = f2b(v.x); u.y = f2b(v.y); u.z = f2b(v.z); u.w = f2b(v.w);
        ((ushort4*)bufX)[id] = u;
        return;
    }
    id -= PR0;
    if (id < PR1) {
        int K = 128, N = 400;
        int n = id / K, k = id - n * K;
        Wt1[id] = f2b(W1[(size_t)k * N + n]);
        return;
    }
    id -= PR1;
    if (id < PR2) {
        int K = 400, N = 800;
        int n = id / K, k = id - n * K;
        Wt2[id] = f2b(W2[(size_t)k * N + n]);
        return;
    }
    id -= PR2;
    if (id < PR3) {
        int K = 800, N = 64;
        int n = id / K, k = id - n * K;
        Wt3[id] = f2b(W3[(size_t)k * N + n]);
    }
}

// ---------------- bf16 MFMA GEMM: C[M,N](bf16) = A[M,K] * Bt[N,K]^T ----------------
// 128xBN tile, BK=32, 4 waves (2x2); per-wave 64 x BN/2 (4 x BN/32 frags of 16x16x32)

#define LDK 40  // 32 + 8 pad (bf16 elems)

template <int BN>
__global__ __launch_bounds__(256) void gemm_mfma(
    const unsigned short* __restrict__ A, const unsigned short* __restrict__ Bt,
    unsigned short* __restrict__ C, int M, int N, int K) {
    constexpr int NF = BN / 32;
    __shared__ short As[128 * LDK];
    __shared__ short Bs[BN * LDK];
    int tid = threadIdx.x;
    int m0 = blockIdx.y * 128, n0 = blockIdx.x * BN;
    int lane = tid & 63, wid = tid >> 6;
    int wm = wid >> 1, wn = wid & 1;
    int r16 = lane & 15, kg = lane >> 4, k8 = kg * 8;

    f32x4 zero4 = {0.f, 0.f, 0.f, 0.f};
    f32x4 acc[4][NF];
#pragma unroll
    for (int m = 0; m < 4; ++m)
#pragma unroll
        for (int nn = 0; nn < NF; ++nn) acc[m][nn] = zero4;

    bf16x8 zv = {0, 0, 0, 0, 0, 0, 0, 0};

    for (int k0 = 0; k0 < K; k0 += 32) {
#pragma unroll
        for (int i = 0; i < 2; ++i) {
            int c = tid + i * 256;
            int row = c >> 2, off = (c & 3) * 8;
            bf16x8 v = zv;
            int gr = m0 + row, gc = k0 + off;
            if (gr < M && gc + 8 <= K)
                v = *(const bf16x8*)(const void*)(A + (size_t)gr * K + gc);
            *(bf16x8*)(void*)(&As[row * LDK + off]) = v;
        }
#pragma unroll
        for (int i = 0; i < BN / 64; ++i) {
            int c = tid + i * 256;
            int row = c >> 2, off = (c & 3) * 8;
            bf16x8 v = zv;
            int gr = n0 + row, gc = k0 + off;
            if (gr < N && gc + 8 <= K)
                v = *(const bf16x8*)(const void*)(Bt + (size_t)gr * K + gc);
            *(bf16x8*)(void*)(&Bs[row * LDK + off]) = v;
        }
        __syncthreads();
        bf16x8 a[4], b[NF];
#pragma unroll
        for (int m = 0; m < 4; ++m)
            a[m] = *(const bf16x8*)(const void*)(&As[(wm * 64 + m * 16 + r16) * LDK + k8]);
#pragma unroll
        for (int nn = 0; nn < NF; ++nn)
            b[nn] = *(const bf16x8*)(const void*)(&Bs[(wn * (BN / 2) + nn * 16 + r16) * LDK + k8]);
#pragma unroll
        for (int m = 0; m < 4; ++m)
#pragma unroll
            for (int nn = 0; nn < NF; ++nn)
                acc[m][nn] = __builtin_amdgcn_mfma_f32_16x16x32_bf16(a[m], b[nn], acc[m][nn], 0, 0, 0);
        __syncthreads();
    }
#pragma unroll
    for (int m = 0; m < 4; ++m) {
        int row_base = m0 + wm * 64 + m * 16 + kg * 4;
#pragma unroll
        for (int nn = 0; nn < NF; ++nn) {
            int col = n0 + wn * (BN / 2) + nn * 16 + r16;
            if (col < N) {
#pragma unroll
                for (int r = 0; r < 4; ++r) {
                    int row = row_base + r;
                    if (row < M) C[(size_t)row * N + col] = f2b(acc[m][nn][r]);
                }
            }
        }
    }
}

// ---------------- attention left/right dot products (packed uint loads) ----------------
__global__ void elr_kernel(const unsigned short* __restrict__ h, const float* __restrict__ al,
                           const float* __restrict__ ar, float* __restrict__ el,
                           float* __restrict__ er, int H, int F) {
    int n = blockIdx.x;
    int lane = threadIdx.x & 63;
    int hh = threadIdx.x >> 6;
    const unsigned* row = (const unsigned*)(const void*)(h + (size_t)n * H * F + (size_t)hh * F);
    int F2 = F >> 1;
    float sl = 0.f, sr = 0.f;
    for (int f = lane; f < F2; f += 64) {
        unsigned u = row[f];
        float v0 = b2f((unsigned short)(u & 0xffffu));
        float v1 = b2f((unsigned short)(u >> 16));
        int c = hh * F + 2 * f;
        sl += v0 * al[c] + v1 * al[c + 1];
        sr += v0 * ar[c] + v1 * ar[c + 1];
    }
#pragma unroll
    for (int off = 32; off; off >>= 1) {
        sl += __shfl_down(sl, off);
        sr += __shfl_down(sr, off);
    }
    if (lane == 0) {
        el[n * H + hh] = sl;
        er[n * H + hh] = sr;
    }
}

// ---------------- fused softmax + per-dst weighted aggregation (bf16 gather) ----------------
// ACT: 0 = ELU -> bf16 out, 1 = sigmoid -> f32 out. NC = HF/8 chunks, P edge groups.
template <int ACT, int H, int NC, int P>
__global__ __launch_bounds__(256) void aggregate_kernel(
    const unsigned short* __restrict__ hC, const float* __restrict__ el,
    const float* __restrict__ er, const int* __restrict__ offsets,
    const int* __restrict__ csrc, const float* __restrict__ bias,
    void* __restrict__ out) {
    constexpr int HF = NC * 8;
    constexpr int F = HF / H;
    int n = blockIdx.x;
    int tid = threadIdx.x;
    int lane = tid & 63;
    int start = offsets[n], deg = offsets[n + 1] - start;

    __shared__ int s_src[64];
    __shared__ float s_alpha[64 * H];
    __shared__ float s_m[H], s_d[H];
    __shared__ float s_part[(P > 1 ? (P - 1) : 1) * NC * 8];

    bool small = deg <= 64;

    // ---- phase 0: wave 0 computes alpha (deg<=64: fully in-register) ----
    if (tid < 64 && deg > 0) {
        float ern[H];
#pragma unroll
        for (int h = 0; h < H; ++h) ern[h] = er[n * H + h];
        if (small) {
            bool act = lane < deg;
            float sh[H];
#pragma unroll
            for (int h = 0; h < H; ++h) sh[h] = -3.402823466e38f;
            if (act) {
                int sc = csrc[start + lane];
                s_src[lane] = sc;
                if constexpr (H == 4) {
                    float4 e4 = *(const float4*)(el + (size_t)sc * 4);
                    float tv[4] = {e4.x, e4.y, e4.z, e4.w};
#pragma unroll
                    for (int h = 0; h < 4; ++h) {
                        float v = tv[h] + ern[h];
                        sh[h] = v > 0.f ? v : 0.2f * v;
                    }
                } else {
#pragma unroll
                    for (int h = 0; h < H; ++h) {
                        float v = el[sc * H + h] + ern[h];
                        sh[h] = v > 0.f ? v : 0.2f * v;
                    }
                }
            }
            float m[H], e[H], s[H];
#pragma unroll
            for (int h = 0; h < H; ++h) {
                m[h] = sh[h];
#pragma unroll
                for (int off = 32; off; off >>= 1) m[h] = fmaxf(m[h], __shfl_xor(m[h], off));
            }
#pragma unroll
            for (int h = 0; h < H; ++h) {
                e[h] = act ? expf(sh[h] - m[h]) : 0.f;
                s[h] = e[h];
#pragma unroll
                for (int off = 32; off; off >>= 1) s[h] += __shfl_xor(s[h], off);
            }
            if (act) {
#pragma unroll
                for (int h = 0; h < H; ++h)
                    s_alpha[lane * H + h] = e[h] / (s[h] + 1e-9f);
            }
        } else {
            // rare: deg > 64 — chunked max/denominator
            float m[H], s[H];
#pragma unroll
            for (int h = 0; h < H; ++h) { m[h] = -3.402823466e38f; s[h] = 0.f; }
            for (int c0 = 0; c0 < deg; c0 += 64) {
                if (c0 + lane < deg) {
                    int sc = csrc[start + c0 + lane];
#pragma unroll
                    for (int h = 0; h < H; ++h) {
                        float v = el[sc * H + h] + ern[h];
                        v = v > 0.f ? v : 0.2f * v;
                        m[h] = fmaxf(m[h], v);
                    }
                }
            }
#pragma unroll
            for (int h = 0; h < H; ++h)
#pragma unroll
                for (int off = 32; off; off >>= 1) m[h] = fmaxf(m[h], __shfl_xor(m[h], off));
            for (int c0 = 0; c0 < deg; c0 += 64) {
                if (c0 + lane < deg) {
                    int sc = csrc[start + c0 + lane];
#pragma unroll
                    for (int h = 0; h < H; ++h) {
                        float v = el[sc * H + h] + ern[h];
                        v = v > 0.f ? v : 0.2f * v;
                        s[h] += expf(v - m[h]);
                    }
                }
            }
#pragma unroll
            for (int h = 0; h < H; ++h)
#pragma unroll
                for (int off = 32; off; off >>= 1) s[h] += __shfl_xor(s[h], off);
            if (lane == 0) {
#pragma unroll
                for (int h = 0; h < H; ++h) {
                    s_m[h] = m[h];
                    s_d[h] = s[h] + 1e-9f;
                }
            }
        }
    }
    __syncthreads();

    bool active = tid < NC * P;
    int slot = tid % NC;
    int q = tid / NC;
    int h0 = (slot * 8) / F, h1 = (slot * 8 + 7) / F;
    int split = (h0 == h1) ? 8 : (h1 * F - slot * 8);
    float acc[8] = {0.f, 0.f, 0.f, 0.f, 0.f, 0.f, 0.f, 0.f};

    if (small) {
        if (active) {
            if (h0 == h1) {
                for (int k = q; k < deg; k += P) {
                    const unsigned short* row = hC + (size_t)s_src[k] * HF;
                    bf16x8 v = *(const bf16x8*)(const void*)(row + slot * 8);
                    float a0 = s_alpha[k * H + h0];
#pragma unroll
                    for (int j = 0; j < 8; ++j) acc[j] += b2f((unsigned short)v[j]) * a0;
                }
            } else {
                for (int k = q; k < deg; k += P) {
                    const unsigned short* row = hC + (size_t)s_src[k] * HF;
                    bf16x8 v = *(const bf16x8*)(const void*)(row + slot * 8);
                    float a0 = s_alpha[k * H + h0];
                    float a1 = s_alpha[k * H + h1];
#pragma unroll
                    for (int j = 0; j < 8; ++j) {
                        float a = (j < split) ? a0 : a1;
                        acc[j] += b2f((unsigned short)v[j]) * a;
                    }
                }
            }
        }
        __syncthreads();
    } else {
        float ern[H];
#pragma unroll
        for (int h = 0; h < H; ++h) ern[h] = er[n * H + h];
        for (int c0 = 0; c0 < deg; c0 += 64) {
            int cn = min(64, deg - c0);
            if (tid < cn) {
                int sc = csrc[start + c0 + tid];
                s_src[tid] = sc;
#pragma unroll
                for (int h = 0; h < H; ++h) {
                    float v = el[sc * H + h] + ern[h];
                    v = v > 0.f ? v : 0.2f * v;
                    s_alpha[tid * H + h] = expf(v - s_m[h]) / s_d[h];
                }
            }
            __syncthreads();
            if (active) {
                for (int k = q; k < cn; k += P) {
                    const unsigned short* row = hC + (size_t)s_src[k] * HF;
                    bf16x8 v = *(const bf16x8*)(const void*)(row + slot * 8);
                    float a0 = s_alpha[k * H + h0];
                    float a1 = s_alpha[k * H + h1];
#pragma unroll
                    for (int j = 0; j < 8; ++j) {
                        float a = (j < split) ? a0 : a1;
                        acc[j] += b2f((unsigned short)v[j]) * a;
                    }
                }
            }
            __syncthreads();
        }
    }

    if constexpr (P > 1) {
        if (active && q > 0) {
#pragma unroll
            for (int j = 0; j < 8; ++j) s_part[((q - 1) * NC + slot) * 8 + j] = acc[j];
        }
        __syncthreads();
        if (tid < NC) {
            for (int qq = 1; qq < P; ++qq)
#pragma unroll
                for (int j = 0; j < 8; ++j) acc[j] += s_part[((qq - 1) * NC + slot) * 8 + j];
        }
    }

    if (tid < NC) {
        float4 bA = *(const float4*)(bias + slot * 8);
        float4 bB = *(const float4*)(bias + slot * 8 + 4);
        float bb[8] = {bA.x, bA.y, bA.z, bA.w, bB.x, bB.y, bB.z, bB.w};
        float v[8];
#pragma unroll
        for (int j = 0; j < 8; ++j) v[j] = acc[j] + bb[j];
        if (ACT == 0) {
            bf16x8 u;
#pragma unroll
            for (int j = 0; j < 8; ++j) {
                float w = v[j] > 0.f ? v[j] : expm1f(v[j]);
                u[j] = (short)f2b(w);
            }
            *(bf16x8*)(void*)((unsigned short*)out + (size_t)n * HF + slot * 8) = u;
        } else {
            float4 oA, oB;
            oA.x = 1.f / (1.f + expf(-v[0]));
            oA.y = 1.f / (1.f + expf(-v[1]));
            oA.z = 1.f / (1.f + expf(-v[2]));
            oA.w = 1.f / (1.f + expf(-v[3]));
            oB.x = 1.f / (1.f + expf(-v[4]));
            oB.y = 1.f / (1.f + expf(-v[5]));
            oB.z = 1.f / (1.f + expf(-v[6]));
            oB.w = 1.f / (1.f + expf(-v[7]));
            float* op = (float*)out + (size_t)n * HF + slot * 8;
            *(float4*)op = oA;
            *(float4*)(op + 4) = oB;
        }
    }
}

// ---------------- launch ----------------

extern "C" void kernel_launch(void* const* d_in, const int* in_sizes, int n_in,
                              void* d_out, int out_size, void* d_ws, size_t ws_size,
                              hipStream_t stream) {
    const float* x   = (const float*)d_in[0];
    const int*   src = (const int*)d_in[1];
    const int*   dst = (const int*)d_in[2];
    const float* W1  = (const float*)d_in[3];
    const float* al1 = (const float*)d_in[4];
    const float* ar1 = (const float*)d_in[5];
    const float* b1  = (const float*)d_in[6];
    const float* W2  = (const float*)d_in[7];
    const float* al2 = (const float*)d_in[8];
    const float* ar2 = (const float*)d_in[9];
    const float* b2  = (const float*)d_in[10];
    const float* W3  = (const float*)d_in[11];
    const float* al3 = (const float*)d_in[12];
    const float* ar3 = (const float*)d_in[13];
    const float* b3  = (const float*)d_in[14];
    float* out = (float*)d_out;

    char* ws = (char*)d_ws;
    size_t off = 0;
    auto alloc = [&](size_t bytes) -> char* {
        char* p = ws + off;
        off += (bytes + 255) & ~(size_t)255;
        return p;
    };
    int* offsets = (int*)alloc((N_NODES + 1) * sizeof(int));
    int* cursor  = (int*)alloc(N_NODES * sizeof(int));
    int* deg     = (int*)alloc(N_NODES * sizeof(int));
    int* csrc    = (int*)alloc(N_EDGES * sizeof(int));
    float* el    = (float*)alloc((size_t)N_NODES * 4 * sizeof(float));
    float* er    = (float*)alloc((size_t)N_NODES * 4 * sizeof(float));
    unsigned short* bufX = (unsigned short*)alloc((size_t)N_NODES * 800 * 2);
    unsigned short* bufH = (unsigned short*)alloc((size_t)N_NODES * 800 * 2);
    unsigned short* Wt1  = (unsigned short*)alloc((size_t)PR1 * 2);
    unsigned short* Wt2  = (unsigned short*)alloc((size_t)PR2 * 2);
    unsigned short* Wt3  = (unsigned short*)alloc((size_t)PR3 * 2);

    // fused prep: x->bf16 + W1/W2/W3 transpose-casts (independent of CSR)
    {
        int total = PR0 + PR1 + PR2 + PR3;
        prep_kernel<<<(total + 255) / 256, 256, 0, stream>>>(x, W1, W2, W3, bufX, Wt1, Wt2, Wt3);
    }

    // CSR build (dst-indexed)
    zero2_kernel<<<(N_NODES + 255) / 256, 256, 0, stream>>>(deg, cursor, N_NODES);
    hist_kernel<<<(N_EDGES + 255) / 256, 256, 0, stream>>>(dst, deg);
    scan_kernel<<<1, SCAN_T, 0, stream>>>(deg, offsets);
    scatter_kernel<<<(N_EDGES + 255) / 256, 256, 0, stream>>>(dst, src, offsets, cursor, csrc);

    // ---- layer 1: [20000,128]x[128,400], H=4 F=100, ELU ----
    {
        int K = 128, N = 400, H = 4, F = 100;
        dim3 grid((N + 127) / 128, (N_NODES + 127) / 128);
        gemm_mfma<128><<<grid, 256, 0, stream>>>(bufX, Wt1, bufH, N_NODES, N, K);
        elr_kernel<<<N_NODES, H * 64, 0, stream>>>(bufH, al1, ar1, el, er, H, F);
        aggregate_kernel<0, 4, 50, 4><<<N_NODES, 256, 0, stream>>>(bufH, el, er, offsets, csrc, b1, bufX);
    }
    // ---- layer 2: [20000,400]x[400,800], H=4 F=200, ELU ----
    {
        int K = 400, N = 800, H = 4, F = 200;
        dim3 grid((N + 127) / 128, (N_NODES + 127) / 128);
        gemm_mfma<128><<<grid, 256, 0, stream>>>(bufX, Wt2, bufH, N_NODES, N, K);
        elr_kernel<<<N_NODES, H * 64, 0, stream>>>(bufH, al2, ar2, el, er, H, F);
        aggregate_kernel<0, 4, 100, 2><<<N_NODES, 256, 0, stream>>>(bufH, el, er, offsets, csrc, b2, bufX);
    }
    // ---- layer 3: [20000,800]x[800,64], H=1 F=64, sigmoid -> d_out ----
    {
        int K = 800, N = 64, F = 64;
        dim3 grid(1, (N_NODES + 127) / 128);
        gemm_mfma<64><<<grid, 256, 0, stream>>>(bufX, Wt3, bufH, N_NODES, N, K);
        elr_kernel<<<N_NODES, 64, 0, stream>>>(bufH, al3, ar3, el, er, 1, F);
        aggregate_kernel<1, 1, 8, 8><<<N_NODES, 256, 0, stream>>>(bufH, el, er, offsets, csrc, b3, out);
    }
}